// Round 2
// baseline (4000.789 us; speedup 1.0000x reference)
//
#include <hip/hip_runtime.h>

// QuantizedTokenizer: encoder MLP -> VQ argmin -> gather -> decoder MLP.
// B=32, Q=1024 -> N=32768 rows. H=1024, HR=512, C=4096.
//
// R2: VQ distance search moved to the matrix pipe. bf16 MFMA computes coarse
// distances (pruner); exact fp32 recheck of provably-sufficient candidate
// groups makes the argmin decision (decider). Margin = 0.05*sqrt(z2*cb2max)
// vs rigorous worst-case coarse error 0.032*sqrt(z2*cb2max) (u=2^-8 RNE).
// MLP GEMMs unchanged (fp32 register-tiled).

#define BM 128
#define BN 128
#define BK 16
#define TM 8
#define TN 8

#define NROW 32768
#define HDIM 1024
#define HRDIM 512
#define CODES 4096

typedef __attribute__((ext_vector_type(8))) short bf16x8;
typedef __attribute__((ext_vector_type(4))) float f32x4;

// ---------------------------------------------------------------------------
// Generic fp32 GEMM: C[M,N] = act(A[M,K] @ B[K,N] + bias[N])  (unchanged R1)
// ---------------------------------------------------------------------------
__global__ __launch_bounds__(256) void sgemm_bias(
    const float* __restrict__ A, const float* __restrict__ B,
    const float* __restrict__ bias, float* __restrict__ C,
    int M, int N, int K, int do_relu)
{
    __shared__ __align__(16) float As[BK][BM + 4];
    __shared__ __align__(16) float Bs[BK][BN + 4];

    const int tid = threadIdx.x;
    const int tx = tid & 15;
    const int ty = tid >> 4;
    const int block_row = blockIdx.y * BM;
    const int block_col = blockIdx.x * BN;

    float acc[TM][TN] = {};

    const int a_r0 = tid >> 2;
    const int a_c0 = (tid & 3) << 2;
    const int b_r0 = tid >> 5;
    const int b_c0 = (tid & 31) << 2;

    const float* Ab = A + (size_t)block_row * K;

    for (int k0 = 0; k0 < K; k0 += BK) {
#pragma unroll
        for (int i = 0; i < 2; ++i) {
            int r = a_r0 + i * 64;
            float4 v = *(const float4*)(Ab + (size_t)r * K + k0 + a_c0);
            As[a_c0 + 0][r] = v.x;
            As[a_c0 + 1][r] = v.y;
            As[a_c0 + 2][r] = v.z;
            As[a_c0 + 3][r] = v.w;
        }
#pragma unroll
        for (int i = 0; i < 2; ++i) {
            int r = b_r0 + i * 8;
            float4 v = *(const float4*)(B + (size_t)(k0 + r) * N + block_col + b_c0);
            *(float4*)(&Bs[r][b_c0]) = v;
        }
        __syncthreads();
#pragma unroll
        for (int k = 0; k < BK; ++k) {
            float4 a0 = *(const float4*)(&As[k][ty * 8]);
            float4 a1 = *(const float4*)(&As[k][ty * 8 + 4]);
            float4 b0 = *(const float4*)(&Bs[k][tx * 4]);
            float4 b1 = *(const float4*)(&Bs[k][tx * 4 + 64]);
            float am[TM] = {a0.x, a0.y, a0.z, a0.w, a1.x, a1.y, a1.z, a1.w};
            float bn[TN] = {b0.x, b0.y, b0.z, b0.w, b1.x, b1.y, b1.z, b1.w};
#pragma unroll
            for (int i = 0; i < TM; ++i)
#pragma unroll
                for (int j = 0; j < TN; ++j)
                    acc[i][j] = fmaf(am[i], bn[j], acc[i][j]);
        }
        __syncthreads();
    }

    float4 bv0 = *(const float4*)(bias + block_col + tx * 4);
    float4 bv1 = *(const float4*)(bias + block_col + 64 + tx * 4);
#pragma unroll
    for (int i = 0; i < TM; ++i) {
        int gr = block_row + ty * TM + i;
        float* Crow = C + (size_t)gr * N + block_col;
        float4 v0, v1;
        v0.x = acc[i][0] + bv0.x;  v0.y = acc[i][1] + bv0.y;
        v0.z = acc[i][2] + bv0.z;  v0.w = acc[i][3] + bv0.w;
        v1.x = acc[i][4] + bv1.x;  v1.y = acc[i][5] + bv1.y;
        v1.z = acc[i][6] + bv1.z;  v1.w = acc[i][7] + bv1.w;
        if (do_relu) {
            v0.x = fmaxf(v0.x, 0.0f); v0.y = fmaxf(v0.y, 0.0f);
            v0.z = fmaxf(v0.z, 0.0f); v0.w = fmaxf(v0.w, 0.0f);
            v1.x = fmaxf(v1.x, 0.0f); v1.y = fmaxf(v1.y, 0.0f);
            v1.z = fmaxf(v1.z, 0.0f); v1.w = fmaxf(v1.w, 0.0f);
        }
        *(float4*)(Crow + tx * 4) = v0;
        *(float4*)(Crow + 64 + tx * 4) = v1;
    }
}

// ---------------------------------------------------------------------------
// codebook row sumsq + global max(cb2) (positive floats: uint-bit atomicMax).
// ---------------------------------------------------------------------------
__global__ __launch_bounds__(256) void cb2_kernel(const float* __restrict__ CB,
                                                  float* __restrict__ cb2,
                                                  unsigned int* __restrict__ cb2max)
{
    int row = blockIdx.x * 4 + (threadIdx.x >> 6);
    int lane = threadIdx.x & 63;
    const float* cr = CB + (size_t)row * HRDIM;
    float s = 0.0f;
#pragma unroll
    for (int i = 0; i < 2; ++i) {
        int c = lane * 4 + i * 256;
        float4 v = *(const float4*)(cr + c);
        s = fmaf(v.x, v.x, s);
        s = fmaf(v.y, v.y, s);
        s = fmaf(v.z, v.z, s);
        s = fmaf(v.w, v.w, s);
    }
#pragma unroll
    for (int off = 32; off > 0; off >>= 1) s += __shfl_down(s, off, 64);
    if (lane == 0) {
        cb2[row] = s;
        atomicMax(cb2max, __float_as_uint(s));  // s > 0: uint order == float order
    }
}

// ---------------------------------------------------------------------------
// fp32 -> bf16 (round-nearest-even), 8 elems/thread.
// ---------------------------------------------------------------------------
__device__ __forceinline__ unsigned short f2bf(float f)
{
    unsigned int u = __float_as_uint(f);
    return (unsigned short)((u + 0x7FFFu + ((u >> 16) & 1u)) >> 16);
}

__global__ __launch_bounds__(256) void to_bf16(const float* __restrict__ in,
                                               unsigned short* __restrict__ out,
                                               int nvec)  // nvec = elems/8
{
    int i = blockIdx.x * 256 + threadIdx.x;
    if (i >= nvec) return;
    float4 a = ((const float4*)in)[2 * i];
    float4 b = ((const float4*)in)[2 * i + 1];
    ushort4 o0, o1;
    o0.x = f2bf(a.x); o0.y = f2bf(a.y); o0.z = f2bf(a.z); o0.w = f2bf(a.w);
    o1.x = f2bf(b.x); o1.y = f2bf(b.y); o1.z = f2bf(b.z); o1.w = f2bf(b.w);
    ((ushort4*)out)[2 * i] = o0;
    ((ushort4*)out)[2 * i + 1] = o1;
}

// ---------------------------------------------------------------------------
// Coarse distance GEMM (bf16 MFMA): per-(row, 32-col-group) min of
// d_coarse = cb2[c] - 2*<zh_row, cbh_c>. 128x128 tile, BK=64, 4 waves (2x2),
// each wave 64x64 via 4x4 of 16x16x32 fragments. XOR-swizzled LDS
// (byte ^= (row&7)<<4) on both write and read sides (rule 21).
// Identical k-addressing for A and B fragments => any k-permutation cancels.
// C/D layout (m89): col = lane&15, row = (lane>>4)*4 + reg.
// ---------------------------------------------------------------------------
__global__ __launch_bounds__(256) void coarse_dist(
    const unsigned short* __restrict__ Zh, const unsigned short* __restrict__ CBh,
    const float* __restrict__ cb2, float* __restrict__ localmin)
{
    __shared__ __align__(16) unsigned short As[128 * 64];
    __shared__ __align__(16) unsigned short Bs[128 * 64];
    __shared__ __align__(16) float sm[128][4];

    const int tid = threadIdx.x;
    const int lane = tid & 63;
    const int w = tid >> 6;           // wave 0..3
    const int wr = w >> 1, wc = w & 1;
    const int block_row = blockIdx.y * 128;   // z rows
    const int block_col = blockIdx.x * 128;   // codes

    f32x4 acc[4][4] = {};

    for (int k0 = 0; k0 < HRDIM; k0 += 64) {
#pragma unroll
        for (int i = 0; i < 4; ++i) {
            int e = (tid + i * 256) * 8;     // element index in 128x64 tile
            int r = e >> 6;
            int c = e & 63;
            int addr = (r * 128 + c * 2) ^ ((r & 7) << 4);   // swizzled byte
            uint4 va = *(const uint4*)(Zh + (size_t)(block_row + r) * HRDIM + k0 + c);
            *(uint4*)((char*)As + addr) = va;
            uint4 vb = *(const uint4*)(CBh + (size_t)(block_col + r) * HRDIM + k0 + c);
            *(uint4*)((char*)Bs + addr) = vb;
        }
        __syncthreads();
#pragma unroll
        for (int kk = 0; kk < 2; ++kk) {
            bf16x8 af[4], bfr[4];
#pragma unroll
            for (int m = 0; m < 4; ++m) {
                int R = wr * 64 + m * 16 + (lane & 15);
                int byte = (R * 128 + (kk * 32 + (lane >> 4) * 8) * 2) ^ ((R & 7) << 4);
                af[m] = *(const bf16x8*)((const char*)As + byte);
            }
#pragma unroll
            for (int n = 0; n < 4; ++n) {
                int R = wc * 64 + n * 16 + (lane & 15);
                int byte = (R * 128 + (kk * 32 + (lane >> 4) * 8) * 2) ^ ((R & 7) << 4);
                bfr[n] = *(const bf16x8*)((const char*)Bs + byte);
            }
#pragma unroll
            for (int m = 0; m < 4; ++m)
#pragma unroll
                for (int n = 0; n < 4; ++n)
                    acc[m][n] = __builtin_amdgcn_mfma_f32_16x16x32_bf16(
                        af[m], bfr[n], acc[m][n], 0, 0, 0);
        }
        __syncthreads();
    }

    // epilogue: per-(row, 32-col-group) min -> sm -> coalesced float4 store
    float c2[4];
#pragma unroll
    for (int n = 0; n < 4; ++n)
        c2[n] = cb2[block_col + wc * 64 + n * 16 + (lane & 15)];

#pragma unroll
    for (int m = 0; m < 4; ++m) {
#pragma unroll
        for (int g = 0; g < 2; ++g) {      // two 32-col groups per wave tile
#pragma unroll
            for (int q = 0; q < 4; ++q) {
                float d0 = c2[g * 2 + 0] - 2.0f * acc[m][g * 2 + 0][q];
                float d1 = c2[g * 2 + 1] - 2.0f * acc[m][g * 2 + 1][q];
                float v = fminf(d0, d1);
#pragma unroll
                for (int msk = 1; msk < 16; msk <<= 1)
                    v = fminf(v, __shfl_xor(v, msk, 64));
                if ((lane & 15) == 0) {
                    int rl = wr * 64 + m * 16 + (lane >> 4) * 4 + q;
                    sm[rl][wc * 2 + g] = v;
                }
            }
        }
    }
    __syncthreads();
    if (tid < 128) {
        float4 v4 = *(const float4*)(&sm[tid][0]);
        *(float4*)(localmin + (size_t)(block_row + tid) * 128 + (block_col >> 5)) = v4;
    }
}

// ---------------------------------------------------------------------------
// Exact recheck: one block per row. thr = min(localmin) + margin; for every
// qualifying 32-col group compute exact fp32 d = cb2[c] - 2*<z,c>, pick
// packed min (tie -> lowest col). True argmin's group provably qualifies.
// ---------------------------------------------------------------------------
__device__ __forceinline__ unsigned int float_orderkey(float f)
{
    unsigned int u = __float_as_uint(f);
    return (u & 0x80000000u) ? ~u : (u | 0x80000000u);
}

__global__ __launch_bounds__(256) void recheck(
    const float* __restrict__ Z, const float* __restrict__ CB,
    const float* __restrict__ cb2, const float* __restrict__ localmin,
    const unsigned int* __restrict__ cb2max,
    unsigned long long* __restrict__ packed)
{
    __shared__ __align__(16) float zs[HRDIM];
    __shared__ float lm[128];
    __shared__ float red[8];
    __shared__ unsigned long long bred[4];

    const int row = blockIdx.x;
    const int tid = threadIdx.x;

    float2 zv = ((const float2*)(Z + (size_t)row * HRDIM))[tid];
    ((float2*)zs)[tid] = zv;
    float z2p = zv.x * zv.x + zv.y * zv.y;
#pragma unroll
    for (int off = 32; off > 0; off >>= 1) z2p += __shfl_down(z2p, off, 64);

    float lmv = 1e30f;
    if (tid < 128) {
        lmv = localmin[(size_t)row * 128 + tid];
        lm[tid] = lmv;
    }
#pragma unroll
    for (int off = 32; off > 0; off >>= 1)
        lmv = fminf(lmv, __shfl_down(lmv, off, 64));
    if ((tid & 63) == 0) {
        red[tid >> 6] = z2p;
        red[4 + (tid >> 6)] = lmv;
    }
    __syncthreads();
    const float z2 = red[0] + red[1] + red[2] + red[3];
    const float m = fminf(fminf(red[4], red[5]), fminf(red[6], red[7]));
    // rigorous coarse-error bound: 2*(2u+u^2)*||z||*||c|| = 0.0157*sqrt(z2*cb2max)
    // threshold adds 2x that (error both directions) with 1.6x headroom.
    const float thr = m + 0.05f * sqrtf(z2 * __uint_as_float(*cb2max)) + 0.01f;

    const int col_in_g = tid >> 3;   // 0..31
    const int sub = tid & 7;
    unsigned long long best = 0xFFFFFFFFFFFFFFFFull;

    for (int g = 0; g < 128; ++g) {
        if (lm[g] <= thr) {
            int c = g * 32 + col_in_g;
            const float4* cbp = (const float4*)(CB + (size_t)c * HRDIM) + sub * 16;
            const float4* zp = (const float4*)zs + sub * 16;
            float dot = 0.0f;
#pragma unroll
            for (int j = 0; j < 16; ++j) {
                float4 cv = cbp[j];
                float4 zq = zp[j];
                dot = fmaf(cv.x, zq.x, dot);
                dot = fmaf(cv.y, zq.y, dot);
                dot = fmaf(cv.z, zq.z, dot);
                dot = fmaf(cv.w, zq.w, dot);
            }
#pragma unroll
            for (int off = 4; off > 0; off >>= 1) dot += __shfl_down(dot, off, 64);
            if (sub == 0) {
                float d = cb2[c] - 2.0f * dot;
                unsigned long long p =
                    ((unsigned long long)float_orderkey(d) << 32) | (unsigned int)c;
                best = (p < best) ? p : best;
            }
        }
    }
#pragma unroll
    for (int off = 32; off > 0; off >>= 1) {
        unsigned long long o = __shfl_down(best, off, 64);
        best = (o < best) ? o : best;
    }
    if ((tid & 63) == 0) bred[tid >> 6] = best;
    __syncthreads();
    if (tid == 0) {
        unsigned long long b = bred[0];
        b = (bred[1] < b) ? bred[1] : b;
        b = (bred[2] < b) ? bred[2] : b;
        b = (bred[3] < b) ? bred[3] : b;
        packed[row] = b;
    }
}

// ---------------------------------------------------------------------------
// Gather pass (unchanged): quantized rows, float(idx), commit partials.
// ---------------------------------------------------------------------------
__global__ __launch_bounds__(256) void gather_pass(
    const float* __restrict__ Z, const unsigned long long* __restrict__ packed,
    const float* __restrict__ CB, float* __restrict__ Q,
    float* __restrict__ IDX, float* __restrict__ partials)
{
    __shared__ float s[4];
    int row = blockIdx.x * 4 + (threadIdx.x >> 6);
    int lane = threadIdx.x & 63;

    unsigned long long p = packed[row];
    int idx = (int)(unsigned int)(p & 0xFFFFFFFFull);

    const float* zr = Z + (size_t)row * HRDIM;
    const float* cr = CB + (size_t)idx * HRDIM;
    float* qr = Q + (size_t)row * HRDIM;

    float z2 = 0.0f;
#pragma unroll
    for (int i = 0; i < 2; ++i) {
        int c = lane * 4 + i * 256;
        float4 zv = *(const float4*)(zr + c);
        float4 cv = *(const float4*)(cr + c);
        *(float4*)(qr + c) = cv;
        z2 = fmaf(zv.x, zv.x, z2);
        z2 = fmaf(zv.y, zv.y, z2);
        z2 = fmaf(zv.z, zv.z, z2);
        z2 = fmaf(zv.w, zv.w, z2);
    }
#pragma unroll
    for (int off = 32; off > 0; off >>= 1) z2 += __shfl_down(z2, off, 64);

    if (lane == 0) {
        unsigned int u = (unsigned int)(p >> 32);
        unsigned int bits = (u & 0x80000000u) ? (u ^ 0x80000000u) : ~u;
        float dmin = __uint_as_float(bits);
        IDX[row] = (float)idx;
        s[threadIdx.x >> 6] = z2 + dmin;   // == ||z - q||^2
    }
    __syncthreads();
    if (threadIdx.x == 0) partials[blockIdx.x] = s[0] + s[1] + s[2] + s[3];
}

__global__ __launch_bounds__(256) void commit_final(
    const float* __restrict__ partials, int n, float* __restrict__ outv)
{
    __shared__ float s[256];
    float v = 0.0f;
    for (int i = threadIdx.x; i < n; i += 256) v += partials[i];
    s[threadIdx.x] = v;
    __syncthreads();
    for (int st = 128; st > 0; st >>= 1) {
        if (threadIdx.x < st) s[threadIdx.x] += s[threadIdx.x + st];
        __syncthreads();
    }
    if (threadIdx.x == 0)
        outv[0] = 0.25f * s[0] / (float)(NROW * HRDIM);
}

// ---------------------------------------------------------------------------
extern "C" void kernel_launch(void* const* d_in, const int* in_sizes, int n_in,
                              void* d_out, int out_size, void* d_ws, size_t ws_size,
                              hipStream_t stream)
{
    const float* x   = (const float*)d_in[0];
    const float* ew1 = (const float*)d_in[1];
    const float* eb1 = (const float*)d_in[2];
    const float* ew2 = (const float*)d_in[3];
    const float* eb2 = (const float*)d_in[4];
    const float* cb  = (const float*)d_in[5];
    const float* dw1 = (const float*)d_in[6];
    const float* db1 = (const float*)d_in[7];
    const float* dw2 = (const float*)d_in[8];
    const float* db2 = (const float*)d_in[9];

    float* out   = (float*)d_out;
    float* recon = out;                               // 33554432 floats
    float* qst   = out + 33554432;                    // 16777216 floats
    float* idxf  = out + 33554432 + 16777216;         // 32768 floats
    float* loss  = out + 33554432 + 16777216 + 32768; // 1 float

    char* ws = (char*)d_ws;
    float* h = (float*)ws;                                   // 128 MB (enc h / dec h2)
    // VQ-phase overlays inside the (then-dead) h region:
    unsigned short* zh  = (unsigned short*)ws;                       // 32 MB
    unsigned short* cbh = (unsigned short*)(ws + (size_t)33554432);  // 4 MB
    float* localmin = (float*)(ws + (size_t)37748736);               // 16 MB
    unsigned long long* packed =
        (unsigned long long*)(ws + (size_t)134217728);               // 256 KB
    float* cb2      = (float*)(ws + (size_t)134217728 + 262144);     // 16 KB
    float* partials = (float*)(ws + (size_t)134217728 + 262144 + 16384);  // 32 KB
    unsigned int* cb2max =
        (unsigned int*)(ws + (size_t)134217728 + 262144 + 16384 + 32768); // 4 B
    float* z = recon;  // z [32768,512] staged in recon segment (written last)

    hipMemsetAsync(cb2max, 0, 4, stream);
    cb2_kernel<<<CODES / 4, 256, 0, stream>>>(cb, cb2, cb2max);

    // encoder
    sgemm_bias<<<dim3(HDIM / BN, NROW / BM), 256, 0, stream>>>(
        x, ew1, eb1, h, NROW, HDIM, HDIM, 1);
    sgemm_bias<<<dim3(HRDIM / BN, NROW / BM), 256, 0, stream>>>(
        h, ew2, eb2, z, NROW, HRDIM, HDIM, 0);

    // VQ: convert -> coarse MFMA localmin -> exact fp32 recheck -> gather
    to_bf16<<<(NROW * HRDIM / 8 + 255) / 256, 256, 0, stream>>>(
        z, zh, NROW * HRDIM / 8);
    to_bf16<<<(CODES * HRDIM / 8 + 255) / 256, 256, 0, stream>>>(
        cb, cbh, CODES * HRDIM / 8);
    coarse_dist<<<dim3(CODES / 128, NROW / 128), 256, 0, stream>>>(
        zh, cbh, cb2, localmin);
    recheck<<<NROW, 256, 0, stream>>>(z, cb, cb2, localmin, cb2max, packed);
    gather_pass<<<NROW / 4, 256, 0, stream>>>(z, packed, cb, qst, idxf, partials);

    // decoder (reads q from the output buffer; h reused for h2)
    sgemm_bias<<<dim3(HDIM / BN, NROW / BM), 256, 0, stream>>>(
        qst, dw1, db1, h, NROW, HDIM, HRDIM, 1);
    sgemm_bias<<<dim3(HDIM / BN, NROW / BM), 256, 0, stream>>>(
        h, dw2, db2, recon, NROW, HDIM, HDIM, 0);

    commit_final<<<1, 256, 0, stream>>>(partials, NROW / 4, loss);
}